// Round 1
// baseline (35276.782 us; speedup 1.0000x reference)
//
#include <hip/hip_runtime.h>
#include <stdint.h>

// LSTM, E=2048, B=2, T=2048, ALL I/O float32 (per reference dtypes).
// For t>=1 input==h, so gates = h @ (W_ih+W_hh)^T + (b_ih+b_hh).
// v2 restructure:
//  - Wc = fp32(W_ih+W_hh) lives in VGPRs: each thread owns a 4-row x 32-k
//    tile (128 f32 regs). No weight LDS reads at all; full fp32 precision.
//  - Thread mapping: wave wv covers k-slice [wv*256, wv*256+256); lane ->
//    (rg = lane>>3: 4 rows rg*4..+3 of 32; ksl = lane&7: 32-k sub-slice).
//    Per-thread h bytes drop 4x vs 1-row x 128-k mapping.
//  - h in LDS with padded slice stride 36 floats (144 B = 9*16 B): the 8
//    distinct ds_read_b128 addresses per wave instruction map to 8 distinct
//    bank quads -> conflict-free.
//  - Wave-local h exchange: each wave polls exactly its own slice's chunks
//    (disjoint across waves) and needs only lgkmcnt(0), not a barrier.
//    Partials double-buffered by t-parity -> ONE __syncthreads per step.
//  - Cell state c in producer-lane registers; bias hoisted to a register.
// Exchange protocol unchanged from the verified kernel: 8 B [tag|payload]
// chunks through LLC, relaxed agent-scope atomics, tag-validated, no fences.
// Harness re-poisons d_ws between iterations (tags 1..2047 never collide
// with poison 0xAAAAAAAA).

#define E 2048
#define NBLK 256
#define NTHR 512
#define HLDS_B 2304            // padded floats per batch: 64 slices * 36
#define PLS_PAR 4224           // floats per parity: 32 rows * 66 * 2
#define SMEM_MAIN 52352
#define SMEM_PROJ 131072

typedef uint32_t u32;
typedef unsigned long long u64;

__device__ __forceinline__ float sigf(float x){ return 1.0f / (1.0f + __expf(-x)); }

// 16 FMAs: 8 k-values (p0,p1 = batch0; q0,q1 = batch1) against one row's
// weight pair (w0,w1), accumulating into A0 (batch0) and A1 (batch1).
#define FMA16(w0, w1, A0, A1) \
  A0 = fmaf((w0).x, p0.x, A0); A0 = fmaf((w0).y, p0.y, A0); \
  A0 = fmaf((w0).z, p0.z, A0); A0 = fmaf((w0).w, p0.w, A0); \
  A0 = fmaf((w1).x, p1.x, A0); A0 = fmaf((w1).y, p1.y, A0); \
  A0 = fmaf((w1).z, p1.z, A0); A0 = fmaf((w1).w, p1.w, A0); \
  A1 = fmaf((w0).x, q0.x, A1); A1 = fmaf((w0).y, q0.y, A1); \
  A1 = fmaf((w0).z, q0.z, A1); A1 = fmaf((w0).w, q0.w, A1); \
  A1 = fmaf((w1).x, q1.x, A1); A1 = fmaf((w1).y, q1.y, A1); \
  A1 = fmaf((w1).z, q1.z, A1); A1 = fmaf((w1).w, q1.w, A1);

__global__ void __launch_bounds__(NTHR, 2) lstm_kernel(
    const float* __restrict__ xin, const float* __restrict__ Wih,
    const float* __restrict__ Whh, const float* __restrict__ bih,
    const float* __restrict__ bhh, u64* __restrict__ chk,
    float* __restrict__ seqout)
{
  extern __shared__ char smem[];
  float* hlds = (float*)smem;                    // [2][2304] = 18432 B (padded h)
  float* pls  = (float*)(smem + 18432);          // [2][4224] = 33792 B partials
  float* bias = (float*)(smem + 52224);          // [32]

  const int tid  = threadIdx.x;
  const int blk  = blockIdx.x;
  const int e0   = blk << 3;                     // this block owns h elems e0..e0+7
  const int lane = tid & 63;
  const int wv   = tid >> 6;                     // wave 0..7, k-slice [wv*256, +256)
  const int rg   = lane >> 3;                    // row group: rows rg*4..rg*4+3
  const int ksl  = lane & 7;                     // 32-k sub-slice within wave
  const int ks   = (wv << 3) + ksl;              // global 32-k slice 0..63
  const int k0   = ks << 5;

  size_t wofs[4];
  #pragma unroll
  for (int rr = 0; rr < 4; ++rr){
    const int row  = (rg << 2) + rr;             // 0..31 = gate*8 + eoff
    const int grow = ((row >> 3) << 11) + e0 + (row & 7);
    wofs[rr] = (size_t)grow * E + (size_t)k0;
  }

  // ---- fp32 Wc = Wih + Whh, 4x32 tile, into registers (128 VGPRs) ----
  float4 wf[32];
  #pragma unroll
  for (int rr = 0; rr < 4; ++rr){
    const float* pa = Wih + wofs[rr];
    const float* pb = Whh + wofs[rr];
    #pragma unroll
    for (int c = 0; c < 8; ++c){
      float4 a = *(const float4*)(pa + (c << 2));
      float4 b = *(const float4*)(pb + (c << 2));
      wf[(rr << 3) + c] = make_float4(a.x + b.x, a.y + b.y, a.z + b.z, a.w + b.w);
    }
  }

  if (tid < 32){
    const int grow = ((tid >> 3) << 11) + e0 + (tid & 7);
    bias[tid] = bih[grow] + bhh[grow];
  }
  // x for t=0, written in the padded h layout
  for (int i = tid; i < 2 * E; i += NTHR){
    const int b = i >> 11, k = i & 2047;
    hlds[b * HLDS_B + (k >> 5) * 36 + (k & 31)] = xin[i];
  }
  __syncthreads();

  const float br = bias[lane & 31];              // hoisted (used by wave 0)
  float creg = 0.0f;                             // cell state (producer lanes)

  // wave-local poll mapping: this wave's 512 chunks (8 per lane), disjoint
  // across waves. chunk value (b, k) -> producer chunk (k>>3)<<4 | b<<3 | k&7
  int cidx[8], cdst[8];
  #pragma unroll
  for (int j = 0; j < 8; ++j){
    const int cl = lane + (j << 6);              // 0..511
    const int b  = cl >> 8;
    const int k  = (wv << 8) + (cl & 255);
    cidx[j] = ((k >> 3) << 4) + (b << 3) + (k & 7);
    cdst[j] = b * HLDS_B + (k >> 5) * 36 + (k & 31);
  }

  const float* hb0 = hlds + ks * 36;             // batch 0, own 32-k slice
  const float* hb1 = hlds + HLDS_B + ks * 36;    // batch 1

  for (int t = 0; t < 2048; ++t){
    if (t > 0){                                  // poll OWN slice only
      const u64* src = chk + ((t & 1) << 12);
      const u32 tag = (u32)t;
      u64 u[8];
      #pragma unroll
      for (int j = 0; j < 8; ++j)
        u[j] = __hip_atomic_load(&src[cidx[j]],
                                 __ATOMIC_RELAXED, __HIP_MEMORY_SCOPE_AGENT);
      int pend = 0xFF;
      while (pend){
        #pragma unroll
        for (int j = 0; j < 8; ++j){
          if (pend & (1 << j)){
            if ((u32)(u[j] >> 32) == tag){
              hlds[cdst[j]] = __uint_as_float((u32)u[j]);
              pend &= ~(1 << j);
            }
          }
        }
        if (pend){
          #pragma unroll
          for (int j = 0; j < 8; ++j)
            if (pend & (1 << j))
              u[j] = __hip_atomic_load(&src[cidx[j]],
                                       __ATOMIC_RELAXED, __HIP_MEMORY_SCOPE_AGENT);
          __builtin_amdgcn_s_sleep(1);
        }
      }
      // wave-synchronous: own ds_writes visible to all lanes of this wave
      asm volatile("s_waitcnt lgkmcnt(0)" ::: "memory");
      __builtin_amdgcn_sched_barrier(0);
    }

    float acc0[4] = {0.f, 0.f, 0.f, 0.f};        // batch 0, rows rg*4..+3
    float acc1[4] = {0.f, 0.f, 0.f, 0.f};        // batch 1
    if (t == 0){                                 // x @ W_ih^T (h=0), fp32 global W
      #pragma unroll
      for (int c8 = 0; c8 < 4; ++c8){
        float4 p0 = *(const float4*)(hb0 + (c8 << 3));
        float4 p1 = *(const float4*)(hb0 + (c8 << 3) + 4);
        float4 q0 = *(const float4*)(hb1 + (c8 << 3));
        float4 q1 = *(const float4*)(hb1 + (c8 << 3) + 4);
        #pragma unroll
        for (int rr = 0; rr < 4; ++rr){
          float4 w0 = *(const float4*)(Wih + wofs[rr] + (c8 << 3));
          float4 w1 = *(const float4*)(Wih + wofs[rr] + (c8 << 3) + 4);
          FMA16(w0, w1, acc0[rr], acc1[rr]);
        }
      }
    } else {                                     // h @ Wc^T, weights in regs
      #pragma unroll
      for (int c8 = 0; c8 < 4; ++c8){
        float4 p0 = *(const float4*)(hb0 + (c8 << 3));
        float4 p1 = *(const float4*)(hb0 + (c8 << 3) + 4);
        float4 q0 = *(const float4*)(hb1 + (c8 << 3));
        float4 q1 = *(const float4*)(hb1 + (c8 << 3) + 4);
        #pragma unroll
        for (int rr = 0; rr < 4; ++rr){
          FMA16(wf[(rr << 3) + (c8 << 1)], wf[(rr << 3) + (c8 << 1) + 1],
                acc0[rr], acc1[rr]);
        }
      }
    }

    {   // partials: [row][ks] float2 (a0,a1), row stride 66 (16B-aligned pad)
      float2* pw = (float2*)(pls + (t & 1) * PLS_PAR);
      #pragma unroll
      for (int rr = 0; rr < 4; ++rr)
        pw[((rg << 2) + rr) * 66 + ks] = make_float2(acc0[rr], acc1[rr]);
    }
    __syncthreads();                             // the ONLY barrier per step

    if (wv == 0){                                // reduce + state update
      const int r = lane & 31;
      const int b = lane >> 5;
      const float* rp = pls + (t & 1) * PLS_PAR + r * 132;
      float4 vs = make_float4(0.f, 0.f, 0.f, 0.f);
      #pragma unroll
      for (int j = 0; j < 32; ++j){              // 64 float2 slots = 32 float4
        float4 v = *(const float4*)(rp + (j << 2));
        vs.x += v.x; vs.y += v.y; vs.z += v.z; vs.w += v.w;
      }
      float s = br + (b ? (vs.y + vs.w) : (vs.x + vs.z));
      const float gi = s;
      const float gf = __shfl(s, (lane + 8)  & 63, 64);
      const float gg = __shfl(s, (lane + 16) & 63, 64);
      const float go = __shfl(s, (lane + 24) & 63, 64);
      if (r < 8){
        const float cn = sigf(gf) * creg + sigf(gi) * tanhf(gg);
        const float hn = sigf(go) * tanhf(cn);
        creg = cn;
        seqout[(((size_t)b << 11) + (size_t)t) * E + e0 + r] = hn;
        if (t < 2047){                           // fire-and-forget tagged chunk
          const u64 pk = ((u64)(u32)(t + 1) << 32) | (u64)__float_as_uint(hn);
          __hip_atomic_store(&chk[(((t + 1) & 1) << 12) + (blk << 4) + (b << 3) + r],
                             pk, __ATOMIC_RELAXED, __HIP_MEMORY_SCOPE_AGENT);
        }
      }
    }
  }
}

// In-place projection: out[row][n] = sum_k h[row][k]*Wout[n][k] + bout[n].
// Block owns 16 rows, staged to LDS first. 2 n-columns per pass halves the
// LDS read instruction count (proj is LDS-issue-bound at 1 wave/SIMD).
__global__ void __launch_bounds__(256, 1) proj_kernel(
    float* __restrict__ io, const float* __restrict__ Wout,
    const float* __restrict__ bout)
{
  extern __shared__ char smem[];
  float* alds = (float*)smem;                  // 16 x 2048 fp32 = 131072 B
  const int tid = threadIdx.x;
  const size_t rbase = (size_t)blockIdx.x * 16 * E;

  for (int idx = tid; idx < 8192; idx += 256){
    float4 v = *(const float4*)(io + rbase + ((size_t)idx << 2));
    *(float4*)(alds + (idx << 2)) = v;
  }
  __syncthreads();

  for (int p = 0; p < 4; ++p){
    const int n0 = (p << 8) + tid;             // column pair: n0, n0+1024
    const int n1 = n0 + 1024;
    const float* wr0 = Wout + (size_t)n0 * E;
    const float* wr1 = Wout + (size_t)n1 * E;
    float acc0[16], acc1[16];
    #pragma unroll
    for (int m = 0; m < 16; ++m){ acc0[m] = 0.0f; acc1[m] = 0.0f; }
    for (int kc = 0; kc < 256; ++kc){
      const float4 a0v = *(const float4*)(wr0 + (kc << 3));
      const float4 a1v = *(const float4*)(wr0 + (kc << 3) + 4);
      const float4 b0v = *(const float4*)(wr1 + (kc << 3));
      const float4 b1v = *(const float4*)(wr1 + (kc << 3) + 4);
      const float* ap = alds + (kc << 3);
      #pragma unroll
      for (int m = 0; m < 16; ++m){
        const float* a = ap + (m << 11);
        float4 x0 = *(const float4*)(a);
        float4 x1 = *(const float4*)(a + 4);
        acc0[m] = fmaf(a0v.x, x0.x, acc0[m]); acc0[m] = fmaf(a0v.y, x0.y, acc0[m]);
        acc0[m] = fmaf(a0v.z, x0.z, acc0[m]); acc0[m] = fmaf(a0v.w, x0.w, acc0[m]);
        acc0[m] = fmaf(a1v.x, x1.x, acc0[m]); acc0[m] = fmaf(a1v.y, x1.y, acc0[m]);
        acc0[m] = fmaf(a1v.z, x1.z, acc0[m]); acc0[m] = fmaf(a1v.w, x1.w, acc0[m]);
        acc1[m] = fmaf(b0v.x, x0.x, acc1[m]); acc1[m] = fmaf(b0v.y, x0.y, acc1[m]);
        acc1[m] = fmaf(b0v.z, x0.z, acc1[m]); acc1[m] = fmaf(b0v.w, x0.w, acc1[m]);
        acc1[m] = fmaf(b1v.x, x1.x, acc1[m]); acc1[m] = fmaf(b1v.y, x1.y, acc1[m]);
        acc1[m] = fmaf(b1v.z, x1.z, acc1[m]); acc1[m] = fmaf(b1v.w, x1.w, acc1[m]);
      }
    }
    const float bo0 = bout[n0];
    const float bo1 = bout[n1];
    #pragma unroll
    for (int m = 0; m < 16; ++m){
      io[rbase + ((size_t)m << 11) + n0] = acc0[m] + bo0;
      io[rbase + ((size_t)m << 11) + n1] = acc1[m] + bo1;
    }
  }
}

extern "C" void kernel_launch(void* const* d_in, const int* in_sizes, int n_in,
                              void* d_out, int out_size, void* d_ws, size_t ws_size,
                              hipStream_t stream)
{
  const float* xin  = (const float*)d_in[0];
  const float* Wih  = (const float*)d_in[1];
  const float* Whh  = (const float*)d_in[2];
  const float* bih  = (const float*)d_in[3];
  const float* bhh  = (const float*)d_in[4];
  const float* Wout = (const float*)d_in[5];
  const float* bout = (const float*)d_in[6];
  float* out = (float*)d_out;

  // chunk buffer: 2 parities x 4096 chunks x 8 B = 64 KB.
  // Poison 0xAAAAAAAA is never a valid tag (tags are 1..2047) -> no init pass.
  u64* chk = (u64*)d_ws;

  hipFuncSetAttribute((const void*)lstm_kernel,
                      hipFuncAttributeMaxDynamicSharedMemorySize, SMEM_MAIN);
  hipFuncSetAttribute((const void*)proj_kernel,
                      hipFuncAttributeMaxDynamicSharedMemorySize, SMEM_PROJ);

  void* args[] = { (void*)&xin, (void*)&Wih, (void*)&Whh, (void*)&bih, (void*)&bhh,
                   (void*)&chk, (void*)&out };
  hipLaunchCooperativeKernel((const void*)lstm_kernel, dim3(NBLK), dim3(NTHR),
                             args, SMEM_MAIN, stream);

  proj_kernel<<<256, 256, SMEM_PROJ, stream>>>(out, Wout, bout);
}

// Round 2
// 10259.440 us; speedup vs baseline: 3.4385x; 3.4385x over previous
//
#include <hip/hip_runtime.h>
#include <hip/hip_fp16.h>
#include <stdint.h>

// LSTM, E=2048, B=2, T=2048, ALL I/O float32 (per reference dtypes).
// For t>=1 input==h, so gates = h @ (W_ih+W_hh)^T + (b_ih+b_hh).
// v3:
//  - Weights as PACKED F16 pairs in VGPRs: each thread owns a 4-row x 32-k
//    tile = 64 half2 regs (v2's fp32 tile was 128 regs and SPILLED: 41 GB
//    scratch FETCH/dispatch). f16 has 3 more mantissa bits than v1's
//    verified bf16. fmaf(__low2float(w),h,acc) -> v_fma_mix_f32.
//  - __launch_bounds__(512, 1): cooperative launch is 1 block/CU anyway;
//    give the allocator the full 512-VGPR budget so nothing spills.
//  - Wave-level __shfl_xor pre-reduce over the 8 k-sub-slices: wave 0's
//    serial reduce drops from 32 LDS b128 reads to 4; partials 16KB->5KB.
//  - Everything verified in v2 kept: padded-h LDS (stride 36 floats,
//    0 bank conflicts measured), wave-local polling (own k-slice only,
//    lgkmcnt-only sync), ONE __syncthreads per step, parity-double-buffered
//    partials, c-state in producer registers.
// Exchange protocol unchanged from the verified kernel: 8 B [tag|payload]
// chunks through L2/LLC, relaxed agent-scope atomics, tag-validated, no
// fences. Poison 0xAAAAAAAA never matches tags 1..2047.

#define E 2048
#define NBLK 256
#define NTHR 512
#define HLDS_B 2304            // padded floats per batch: 64 slices * 36
#define PLS_STRIDE 20          // floats per row slot (16 used + 4 pad)
#define PLS_PAR 640            // floats per parity: 32 rows * 20
#define SMEM_MAIN 23680
#define SMEM_PROJ 131072

typedef uint32_t u32;
typedef unsigned long long u64;

__device__ __forceinline__ float sigf(float x){ return 1.0f / (1.0f + __expf(-x)); }

// one row x 8 k, both batches: 16 FMAs from 4 packed-f16 weight pairs
#define ROWFMA8(W0, W1, W2, W3, A0, A1) \
  A0 = fmaf(__low2float(W0),  p0.x, A0); A0 = fmaf(__high2float(W0), p0.y, A0); \
  A0 = fmaf(__low2float(W1),  p0.z, A0); A0 = fmaf(__high2float(W1), p0.w, A0); \
  A0 = fmaf(__low2float(W2),  p1.x, A0); A0 = fmaf(__high2float(W2), p1.y, A0); \
  A0 = fmaf(__low2float(W3),  p1.z, A0); A0 = fmaf(__high2float(W3), p1.w, A0); \
  A1 = fmaf(__low2float(W0),  q0.x, A1); A1 = fmaf(__high2float(W0), q0.y, A1); \
  A1 = fmaf(__low2float(W1),  q0.z, A1); A1 = fmaf(__high2float(W1), q0.w, A1); \
  A1 = fmaf(__low2float(W2),  q1.x, A1); A1 = fmaf(__high2float(W2), q1.y, A1); \
  A1 = fmaf(__low2float(W3),  q1.z, A1); A1 = fmaf(__high2float(W3), q1.w, A1);

__global__ void __launch_bounds__(NTHR, 1) lstm_kernel(
    const float* __restrict__ xin, const float* __restrict__ Wih,
    const float* __restrict__ Whh, const float* __restrict__ bih,
    const float* __restrict__ bhh, u64* __restrict__ chk,
    float* __restrict__ seqout)
{
  extern __shared__ char smem[];
  float* hlds = (float*)smem;                    // [2][2304] = 18432 B (padded h)
  float* pls  = (float*)(smem + 18432);          // [2][640]  =  5120 B partials
  float* bias = (float*)(smem + 23552);          // [32]

  const int tid  = threadIdx.x;
  const int blk  = blockIdx.x;
  const int e0   = blk << 3;                     // this block owns h elems e0..e0+7
  const int lane = tid & 63;
  const int wv   = tid >> 6;                     // wave 0..7, k-slice [wv*256, +256)
  const int rg   = lane >> 3;                    // row group: rows rg*4..rg*4+3
  const int ksl  = lane & 7;                     // 32-k sub-slice within wave
  const int ks   = (wv << 3) + ksl;              // global 32-k slice 0..63
  const int k0   = ks << 5;

  if (tid < 32){
    const int grow = ((tid >> 3) << 11) + e0 + (tid & 7);
    bias[tid] = bih[grow] + bhh[grow];
  }
  // x for t=0, written in the padded h layout
  for (int i = tid; i < 2 * E; i += NTHR){
    const int b = i >> 11, k = i & 2047;
    hlds[b * HLDS_B + (k >> 5) * 36 + (k & 31)] = xin[i];
  }
  __syncthreads();

  const float* hb0 = hlds + ks * 36;             // batch 0, own 32-k slice
  const float* hb1 = hlds + HLDS_B + ks * 36;    // batch 1

  // ---- fused: build f16 Wc = Wih + Whh into registers (64 half2) AND
  //      compute t=0 gates = x @ W_ih^T in full fp32 (h=0 at t=0) ----
  __half2 wh[64];
  float acc0[4] = {0.f, 0.f, 0.f, 0.f};
  float acc1[4] = {0.f, 0.f, 0.f, 0.f};
  #pragma unroll
  for (int rr = 0; rr < 4; ++rr){
    const int row  = (rg << 2) + rr;             // 0..31 = gate*8 + eoff
    const int grow = ((row >> 3) << 11) + e0 + (row & 7);
    const float* pa = Wih + (size_t)grow * E + k0;
    const float* pb = Whh + (size_t)grow * E + k0;
    #pragma unroll
    for (int c = 0; c < 8; ++c){                 // 4 k per chunk
      float4 a = *(const float4*)(pa + (c << 2));
      float4 b = *(const float4*)(pb + (c << 2));
      wh[(rr << 4) + (c << 1)    ] =
        __halves2half2(__float2half_rn(a.x + b.x), __float2half_rn(a.y + b.y));
      wh[(rr << 4) + (c << 1) + 1] =
        __halves2half2(__float2half_rn(a.z + b.z), __float2half_rn(a.w + b.w));
      float4 x0 = *(const float4*)(hb0 + (c << 2));
      float4 x1 = *(const float4*)(hb1 + (c << 2));
      acc0[rr] = fmaf(a.x, x0.x, acc0[rr]); acc0[rr] = fmaf(a.y, x0.y, acc0[rr]);
      acc0[rr] = fmaf(a.z, x0.z, acc0[rr]); acc0[rr] = fmaf(a.w, x0.w, acc0[rr]);
      acc1[rr] = fmaf(a.x, x1.x, acc1[rr]); acc1[rr] = fmaf(a.y, x1.y, acc1[rr]);
      acc1[rr] = fmaf(a.z, x1.z, acc1[rr]); acc1[rr] = fmaf(a.w, x1.w, acc1[rr]);
    }
  }

  const float br = bias[lane & 31];              // hoisted (used by wave 0)
  float creg = 0.0f;                             // cell state (producer lanes)

  // wave-local poll mapping: this wave's 512 chunks (8 per lane), disjoint
  // across waves. h element (b,k) -> producer chunk (k>>3)<<4 | b<<3 | k&7
  int cidx[8], cdst[8];
  #pragma unroll
  for (int j = 0; j < 8; ++j){
    const int cl = lane + (j << 6);              // 0..511
    const int b  = cl >> 8;
    const int k  = (wv << 8) + (cl & 255);
    cidx[j] = ((k >> 3) << 4) + (b << 3) + (k & 7);
    cdst[j] = b * HLDS_B + (k >> 5) * 36 + (k & 31);
  }

  for (int t = 0; t < 2048; ++t){
    // wave-level pre-reduce across the 8 k-sub-slices (ksl = lane bits 0..2)
    #pragma unroll
    for (int m = 1; m <= 4; m <<= 1){
      #pragma unroll
      for (int rr = 0; rr < 4; ++rr){
        acc0[rr] += __shfl_xor(acc0[rr], m, 64);
        acc1[rr] += __shfl_xor(acc1[rr], m, 64);
      }
    }
    if (ksl == 0){                               // 8 lanes/wave publish partials
      float2* pw = (float2*)(pls + (t & 1) * PLS_PAR);
      #pragma unroll
      for (int rr = 0; rr < 4; ++rr)
        pw[((rg << 2) + rr) * (PLS_STRIDE / 2) + wv] = make_float2(acc0[rr], acc1[rr]);
    }
    __syncthreads();                             // the ONLY barrier per step

    if (wv == 0){                                // reduce 8 wave-partials + update
      const int r = lane & 31;
      const int b = lane >> 5;
      const float* rp = pls + (t & 1) * PLS_PAR + r * PLS_STRIDE;
      float4 v0 = *(const float4*)(rp);
      float4 v1 = *(const float4*)(rp + 4);
      float4 v2 = *(const float4*)(rp + 8);
      float4 v3 = *(const float4*)(rp + 12);
      float s = br + (b ? (v0.y + v0.w + v1.y + v1.w + v2.y + v2.w + v3.y + v3.w)
                        : (v0.x + v0.z + v1.x + v1.z + v2.x + v2.z + v3.x + v3.z));
      const float gi = s;
      const float gf = __shfl(s, (lane + 8)  & 63, 64);
      const float gg = __shfl(s, (lane + 16) & 63, 64);
      const float go = __shfl(s, (lane + 24) & 63, 64);
      if (r < 8){
        const float cn = sigf(gf) * creg + sigf(gi) * tanhf(gg);
        const float hn = sigf(go) * tanhf(cn);
        creg = cn;
        seqout[(((size_t)b << 11) + (size_t)t) * E + e0 + r] = hn;
        if (t < 2047){                           // fire-and-forget tagged chunk
          const u64 pk = ((u64)(u32)(t + 1) << 32) | (u64)__float_as_uint(hn);
          __hip_atomic_store(&chk[(((t + 1) & 1) << 12) + (blk << 4) + (b << 3) + r],
                             pk, __ATOMIC_RELAXED, __HIP_MEMORY_SCOPE_AGENT);
        }
      }
    }
    if (t == 2047) break;

    {                                            // poll OWN slice only
      const u64* src = chk + (((t + 1) & 1) << 12);
      const u32 tag = (u32)(t + 1);
      u64 u[8];
      #pragma unroll
      for (int j = 0; j < 8; ++j)
        u[j] = __hip_atomic_load(&src[cidx[j]],
                                 __ATOMIC_RELAXED, __HIP_MEMORY_SCOPE_AGENT);
      int pend = 0xFF;
      while (pend){
        #pragma unroll
        for (int j = 0; j < 8; ++j){
          if (pend & (1 << j)){
            if ((u32)(u[j] >> 32) == tag){
              hlds[cdst[j]] = __uint_as_float((u32)u[j]);
              pend &= ~(1 << j);
            }
          }
        }
        if (pend){
          #pragma unroll
          for (int j = 0; j < 8; ++j)
            if (pend & (1 << j))
              u[j] = __hip_atomic_load(&src[cidx[j]],
                                       __ATOMIC_RELAXED, __HIP_MEMORY_SCOPE_AGENT);
          __builtin_amdgcn_s_sleep(1);
        }
      }
      // wave-synchronous: own ds_writes visible to all lanes of this wave
      asm volatile("s_waitcnt lgkmcnt(0)" ::: "memory");
      __builtin_amdgcn_sched_barrier(0);
    }

    // compute acc(t+1): h @ Wc^T, weights in f16 registers
    #pragma unroll
    for (int rr = 0; rr < 4; ++rr){ acc0[rr] = 0.f; acc1[rr] = 0.f; }
    #pragma unroll
    for (int c8 = 0; c8 < 4; ++c8){              // 8 k per chunk
      float4 p0 = *(const float4*)(hb0 + (c8 << 3));
      float4 p1 = *(const float4*)(hb0 + (c8 << 3) + 4);
      float4 q0 = *(const float4*)(hb1 + (c8 << 3));
      float4 q1 = *(const float4*)(hb1 + (c8 << 3) + 4);
      #pragma unroll
      for (int rr = 0; rr < 4; ++rr){
        ROWFMA8(wh[(rr << 4) + (c8 << 2)],     wh[(rr << 4) + (c8 << 2) + 1],
                wh[(rr << 4) + (c8 << 2) + 2], wh[(rr << 4) + (c8 << 2) + 3],
                acc0[rr], acc1[rr]);
      }
    }
  }
}

// In-place projection: out[row][n] = sum_k h[row][k]*Wout[n][k] + bout[n].
// Block owns 16 rows, staged to LDS first. 2 n-columns per pass halves the
// LDS read instruction count (proj is LDS-issue-bound at 1 wave/SIMD).
__global__ void __launch_bounds__(256, 1) proj_kernel(
    float* __restrict__ io, const float* __restrict__ Wout,
    const float* __restrict__ bout)
{
  extern __shared__ char smem[];
  float* alds = (float*)smem;                  // 16 x 2048 fp32 = 131072 B
  const int tid = threadIdx.x;
  const size_t rbase = (size_t)blockIdx.x * 16 * E;

  for (int idx = tid; idx < 8192; idx += 256){
    float4 v = *(const float4*)(io + rbase + ((size_t)idx << 2));
    *(float4*)(alds + (idx << 2)) = v;
  }
  __syncthreads();

  for (int p = 0; p < 4; ++p){
    const int n0 = (p << 8) + tid;             // column pair: n0, n0+1024
    const int n1 = n0 + 1024;
    const float* wr0 = Wout + (size_t)n0 * E;
    const float* wr1 = Wout + (size_t)n1 * E;
    float acc0[16], acc1[16];
    #pragma unroll
    for (int m = 0; m < 16; ++m){ acc0[m] = 0.0f; acc1[m] = 0.0f; }
    for (int kc = 0; kc < 256; ++kc){
      const float4 a0v = *(const float4*)(wr0 + (kc << 3));
      const float4 a1v = *(const float4*)(wr0 + (kc << 3) + 4);
      const float4 b0v = *(const float4*)(wr1 + (kc << 3));
      const float4 b1v = *(const float4*)(wr1 + (kc << 3) + 4);
      const float* ap = alds + (kc << 3);
      #pragma unroll
      for (int m = 0; m < 16; ++m){
        const float* a = ap + (m << 11);
        float4 x0 = *(const float4*)(a);
        float4 x1 = *(const float4*)(a + 4);
        acc0[m] = fmaf(a0v.x, x0.x, acc0[m]); acc0[m] = fmaf(a0v.y, x0.y, acc0[m]);
        acc0[m] = fmaf(a0v.z, x0.z, acc0[m]); acc0[m] = fmaf(a0v.w, x0.w, acc0[m]);
        acc0[m] = fmaf(a1v.x, x1.x, acc0[m]); acc0[m] = fmaf(a1v.y, x1.y, acc0[m]);
        acc0[m] = fmaf(a1v.z, x1.z, acc0[m]); acc0[m] = fmaf(a1v.w, x1.w, acc0[m]);
        acc1[m] = fmaf(b0v.x, x0.x, acc1[m]); acc1[m] = fmaf(b0v.y, x0.y, acc1[m]);
        acc1[m] = fmaf(b0v.z, x0.z, acc1[m]); acc1[m] = fmaf(b0v.w, x0.w, acc1[m]);
        acc1[m] = fmaf(b1v.x, x1.x, acc1[m]); acc1[m] = fmaf(b1v.y, x1.y, acc1[m]);
        acc1[m] = fmaf(b1v.z, x1.z, acc1[m]); acc1[m] = fmaf(b1v.w, x1.w, acc1[m]);
      }
    }
    const float bo0 = bout[n0];
    const float bo1 = bout[n1];
    #pragma unroll
    for (int m = 0; m < 16; ++m){
      io[rbase + ((size_t)m << 11) + n0] = acc0[m] + bo0;
      io[rbase + ((size_t)m << 11) + n1] = acc1[m] + bo1;
    }
  }
}

extern "C" void kernel_launch(void* const* d_in, const int* in_sizes, int n_in,
                              void* d_out, int out_size, void* d_ws, size_t ws_size,
                              hipStream_t stream)
{
  const float* xin  = (const float*)d_in[0];
  const float* Wih  = (const float*)d_in[1];
  const float* Whh  = (const float*)d_in[2];
  const float* bih  = (const float*)d_in[3];
  const float* bhh  = (const float*)d_in[4];
  const float* Wout = (const float*)d_in[5];
  const float* bout = (const float*)d_in[6];
  float* out = (float*)d_out;

  // chunk buffer: 2 parities x 4096 chunks x 8 B = 64 KB.
  // Poison 0xAAAAAAAA is never a valid tag (tags are 1..2047) -> no init pass.
  u64* chk = (u64*)d_ws;

  hipFuncSetAttribute((const void*)lstm_kernel,
                      hipFuncAttributeMaxDynamicSharedMemorySize, SMEM_MAIN);
  hipFuncSetAttribute((const void*)proj_kernel,
                      hipFuncAttributeMaxDynamicSharedMemorySize, SMEM_PROJ);

  void* args[] = { (void*)&xin, (void*)&Wih, (void*)&Whh, (void*)&bih, (void*)&bhh,
                   (void*)&chk, (void*)&out };
  hipLaunchCooperativeKernel((const void*)lstm_kernel, dim3(NBLK), dim3(NTHR),
                             args, SMEM_MAIN, stream);

  proj_kernel<<<256, 256, SMEM_PROJ, stream>>>(out, Wout, bout);
}

// Round 3
// 8436.510 us; speedup vs baseline: 4.1814x; 1.2161x over previous
//
#include <hip/hip_runtime.h>
#include <hip/hip_fp16.h>
#include <stdint.h>

// LSTM, E=2048, B=2, T=2048, ALL I/O float32 (per reference dtypes).
// For t>=1 input==h, so gates = h @ (W_ih+W_hh)^T + (b_ih+b_hh).
// v4: attack the ~4 us/step exchange latency (v3 evidence: FETCH shows
// exactly one refetch per chunk-line per XCD per step -> polls were hitting
// stale per-XCD L2 and waiting on cross-die invalidation probes).
//  - Poll loads AND publish stores now bypass L1+L2 via explicit
//    `sc0 sc1` asm (gfx950). Stores land in the memory-side LLC; loads read
//    the LLC directly -> detection = store->LLC + load RTT, no probe wait.
//  - Poll layout: chunk = wv*512 + j*64 + lane, so each load instruction
//    reads 512 contiguous bytes per wave (full 64B lines, no amplification).
//  - Every asm load block drains vmcnt(0) before results are used
//    (untracked-asm vmem only makes compiler waits more conservative).
//  - Fast sigmoid/tanh via __expf + v_rcp on the serial producer tail
//    (libm tanhf is branch-heavy); publish chk BEFORE seqout store.
// Kept from v3 (verified): f16 packed weights in VGPRs (64 half2/thread,
// no spill at VGPR=116), padded-h LDS (stride 36 floats, ~0 conflicts),
// wave-local polling (own k-slice only, lgkmcnt-only sync), ONE
// __syncthreads per step, parity-double-buffered partials, c in registers.
// Protocol: 8 B [tag|payload] chunks, tag-validated (poison 0xAAAAAAAA
// never matches tags 1..2047), relaxed, no fences.

#define E 2048
#define NBLK 256
#define NTHR 512
#define HLDS_B 2304            // padded floats per batch: 64 slices * 36
#define PLS_STRIDE 20          // floats per row slot (16 used + 4 pad)
#define PLS_PAR 640            // floats per parity: 32 rows * 20
#define SMEM_MAIN 23680
#define SMEM_PROJ 131072

typedef uint32_t u32;
typedef unsigned long long u64;

__device__ __forceinline__ float sigf(float x){
  return __builtin_amdgcn_rcpf(1.0f + __expf(-x));
}
__device__ __forceinline__ float tanhfast(float x){
  // 1 - 2/(e^{2x}+1); exp overflow -> rcp(inf)=0 -> 1; underflow -> -1.
  float e = __expf(2.0f * x);
  return 1.0f - 2.0f * __builtin_amdgcn_rcpf(e + 1.0f);
}

// one row x 8 k, both batches: 16 FMAs from 4 packed-f16 weight pairs
#define ROWFMA8(W0, W1, W2, W3, A0, A1) \
  A0 = fmaf(__low2float(W0),  p0.x, A0); A0 = fmaf(__high2float(W0), p0.y, A0); \
  A0 = fmaf(__low2float(W1),  p0.z, A0); A0 = fmaf(__high2float(W1), p0.w, A0); \
  A0 = fmaf(__low2float(W2),  p1.x, A0); A0 = fmaf(__high2float(W2), p1.y, A0); \
  A0 = fmaf(__low2float(W3),  p1.z, A0); A0 = fmaf(__high2float(W3), p1.w, A0); \
  A1 = fmaf(__low2float(W0),  q0.x, A1); A1 = fmaf(__high2float(W0), q0.y, A1); \
  A1 = fmaf(__low2float(W1),  q0.z, A1); A1 = fmaf(__high2float(W1), q0.w, A1); \
  A1 = fmaf(__low2float(W2),  q1.x, A1); A1 = fmaf(__high2float(W2), q1.y, A1); \
  A1 = fmaf(__low2float(W3),  q1.z, A1); A1 = fmaf(__high2float(W3), q1.w, A1);

// tag-check + LDS-deposit for poll slot J (UJ is a named u64 register var)
#define POLLCHK(J, UJ) \
  if (pend & (1 << J)){ \
    if ((u32)(UJ >> 32) == tag){ \
      hlds[cdst[J]] = __uint_as_float((u32)UJ); \
      pend &= ~(1 << J); \
    } \
  }
// LLC-direct reload of slot J (exec-masked by the pend predicate)
#define RELOAD(J, UJ, OFS) \
  if (pend & (1 << J)){ \
    asm volatile("global_load_dwordx2 %0, %1, off offset:" OFS " sc0 sc1" \
                 : "=v"(UJ) : "v"(src) : "memory"); \
  }

__global__ void __launch_bounds__(NTHR, 1) lstm_kernel(
    const float* __restrict__ xin, const float* __restrict__ Wih,
    const float* __restrict__ Whh, const float* __restrict__ bih,
    const float* __restrict__ bhh, u64* __restrict__ chk,
    float* __restrict__ seqout)
{
  extern __shared__ char smem[];
  float* hlds = (float*)smem;                    // [2][2304] = 18432 B (padded h)
  float* pls  = (float*)(smem + 18432);          // [2][640]  =  5120 B partials
  float* bias = (float*)(smem + 23552);          // [32]

  const int tid  = threadIdx.x;
  const int blk  = blockIdx.x;
  const int e0   = blk << 3;                     // this block owns h elems e0..e0+7
  const int lane = tid & 63;
  const int wv   = tid >> 6;                     // wave 0..7, k-slice [wv*256, +256)
  const int rg   = lane >> 3;                    // row group: rows rg*4..rg*4+3
  const int ksl  = lane & 7;                     // 32-k sub-slice within wave
  const int ks   = (wv << 3) + ksl;              // global 32-k slice 0..63
  const int k0   = ks << 5;

  if (tid < 32){
    const int grow = ((tid >> 3) << 11) + e0 + (tid & 7);
    bias[tid] = bih[grow] + bhh[grow];
  }
  // x for t=0, written in the padded h layout
  for (int i = tid; i < 2 * E; i += NTHR){
    const int b = i >> 11, k = i & 2047;
    hlds[b * HLDS_B + (k >> 5) * 36 + (k & 31)] = xin[i];
  }
  __syncthreads();

  const float* hb0 = hlds + ks * 36;             // batch 0, own 32-k slice
  const float* hb1 = hlds + HLDS_B + ks * 36;    // batch 1

  // ---- fused: build f16 Wc = Wih + Whh into registers (64 half2) AND
  //      compute t=0 gates = x @ W_ih^T in full fp32 (h=0 at t=0) ----
  __half2 wh[64];
  float acc0[4] = {0.f, 0.f, 0.f, 0.f};
  float acc1[4] = {0.f, 0.f, 0.f, 0.f};
  #pragma unroll
  for (int rr = 0; rr < 4; ++rr){
    const int row  = (rg << 2) + rr;             // 0..31 = gate*8 + eoff
    const int grow = ((row >> 3) << 11) + e0 + (row & 7);
    const float* pa = Wih + (size_t)grow * E + k0;
    const float* pb = Whh + (size_t)grow * E + k0;
    #pragma unroll
    for (int c = 0; c < 8; ++c){                 // 4 k per chunk
      float4 a = *(const float4*)(pa + (c << 2));
      float4 b = *(const float4*)(pb + (c << 2));
      wh[(rr << 4) + (c << 1)    ] =
        __halves2half2(__float2half_rn(a.x + b.x), __float2half_rn(a.y + b.y));
      wh[(rr << 4) + (c << 1) + 1] =
        __halves2half2(__float2half_rn(a.z + b.z), __float2half_rn(a.w + b.w));
      float4 x0 = *(const float4*)(hb0 + (c << 2));
      float4 x1 = *(const float4*)(hb1 + (c << 2));
      acc0[rr] = fmaf(a.x, x0.x, acc0[rr]); acc0[rr] = fmaf(a.y, x0.y, acc0[rr]);
      acc0[rr] = fmaf(a.z, x0.z, acc0[rr]); acc0[rr] = fmaf(a.w, x0.w, acc0[rr]);
      acc1[rr] = fmaf(a.x, x1.x, acc1[rr]); acc1[rr] = fmaf(a.y, x1.y, acc1[rr]);
      acc1[rr] = fmaf(a.z, x1.z, acc1[rr]); acc1[rr] = fmaf(a.w, x1.w, acc1[rr]);
    }
  }

  const float br = bias[lane & 31];              // hoisted (used by wave 0)
  float creg = 0.0f;                             // cell state (producer lanes)

  // wave-local poll mapping: chunk c = wv*512 + j*64 + lane, so load j is a
  // 512 B contiguous wave read (full 64 B lines -> no fetch amplification).
  // chunk c (block-relative): b=(c>>3)&1, elem e=((c>>4)<<3)|(c&7)
  int cdst[8];
  #pragma unroll
  for (int j = 0; j < 8; ++j){
    const int c = (wv << 9) + (j << 6) + lane;
    const int b = (c >> 3) & 1;
    const int e = ((c >> 4) << 3) | (c & 7);
    cdst[j] = b * HLDS_B + (e >> 5) * 36 + (e & 31);
  }
  u64* const pchk0 = chk;                        // parity 0 base
  u64* const pchk1 = chk + 4096;                 // parity 1 base

  for (int t = 0; t < 2048; ++t){
    // wave-level pre-reduce across the 8 k-sub-slices (ksl = lane bits 0..2)
    #pragma unroll
    for (int m = 1; m <= 4; m <<= 1){
      #pragma unroll
      for (int rr = 0; rr < 4; ++rr){
        acc0[rr] += __shfl_xor(acc0[rr], m, 64);
        acc1[rr] += __shfl_xor(acc1[rr], m, 64);
      }
    }
    if (ksl == 0){                               // 8 lanes/wave publish partials
      float2* pw = (float2*)(pls + (t & 1) * PLS_PAR);
      #pragma unroll
      for (int rr = 0; rr < 4; ++rr)
        pw[((rg << 2) + rr) * (PLS_STRIDE / 2) + wv] = make_float2(acc0[rr], acc1[rr]);
    }
    __syncthreads();                             // the ONLY barrier per step

    if (wv == 0){                                // reduce 8 wave-partials + update
      const int r = lane & 31;
      const int b = lane >> 5;
      const float* rp = pls + (t & 1) * PLS_PAR + r * PLS_STRIDE;
      float4 v0 = *(const float4*)(rp);
      float4 v1 = *(const float4*)(rp + 4);
      float4 v2 = *(const float4*)(rp + 8);
      float4 v3 = *(const float4*)(rp + 12);
      float s = br + (b ? (v0.y + v0.w + v1.y + v1.w + v2.y + v2.w + v3.y + v3.w)
                        : (v0.x + v0.z + v1.x + v1.z + v2.x + v2.z + v3.x + v3.z));
      const float gi = s;
      const float gf = __shfl(s, (lane + 8)  & 63, 64);
      const float gg = __shfl(s, (lane + 16) & 63, 64);
      const float go = __shfl(s, (lane + 24) & 63, 64);
      if (r < 8){
        const float cn = sigf(gf) * creg + sigf(gi) * tanhfast(gg);
        const float hn = sigf(go) * tanhfast(cn);
        creg = cn;
        if (t < 2047){                           // publish FIRST (critical path)
          const u64 pk = ((u64)(u32)(t + 1) << 32) | (u64)__float_as_uint(hn);
          u64* dst = (((t + 1) & 1) ? pchk1 : pchk0) + (blk << 4) + (b << 3) + r;
          asm volatile("global_store_dwordx2 %0, %1, off sc0 sc1"
                       :: "v"(dst), "v"(pk) : "memory");
        }
        seqout[(((size_t)b << 11) + (size_t)t) * E + e0 + r] = hn;
      }
    }
    if (t == 2047) break;

    {                                            // poll OWN slice, LLC-direct
      const u64* src = (((t + 1) & 1) ? pchk1 : pchk0) + (wv << 9) + lane;
      const u32 tag = (u32)(t + 1);
      u64 u0_, u1_, u2_, u3_, u4_, u5_, u6_, u7_;
      asm volatile(
        "global_load_dwordx2 %0, %8, off sc0 sc1\n\t"
        "global_load_dwordx2 %1, %8, off offset:512 sc0 sc1\n\t"
        "global_load_dwordx2 %2, %8, off offset:1024 sc0 sc1\n\t"
        "global_load_dwordx2 %3, %8, off offset:1536 sc0 sc1\n\t"
        "global_load_dwordx2 %4, %8, off offset:2048 sc0 sc1\n\t"
        "global_load_dwordx2 %5, %8, off offset:2560 sc0 sc1\n\t"
        "global_load_dwordx2 %6, %8, off offset:3072 sc0 sc1\n\t"
        "global_load_dwordx2 %7, %8, off offset:3584 sc0 sc1\n\t"
        "s_waitcnt vmcnt(0)"
        : "=&v"(u0_), "=&v"(u1_), "=&v"(u2_), "=&v"(u3_),
          "=&v"(u4_), "=&v"(u5_), "=&v"(u6_), "=&v"(u7_)
        : "v"(src) : "memory");
      int pend = 0xFF;
      while (true){
        POLLCHK(0, u0_) POLLCHK(1, u1_) POLLCHK(2, u2_) POLLCHK(3, u3_)
        POLLCHK(4, u4_) POLLCHK(5, u5_) POLLCHK(6, u6_) POLLCHK(7, u7_)
        if (pend == 0) break;
        __builtin_amdgcn_s_sleep(1);
        RELOAD(0, u0_, "0")    RELOAD(1, u1_, "512")
        RELOAD(2, u2_, "1024") RELOAD(3, u3_, "1536")
        RELOAD(4, u4_, "2048") RELOAD(5, u5_, "2560")
        RELOAD(6, u6_, "3072") RELOAD(7, u7_, "3584")
        asm volatile("s_waitcnt vmcnt(0)" ::: "memory");
      }
      // wave-synchronous: own ds_writes visible to all lanes of this wave
      asm volatile("s_waitcnt lgkmcnt(0)" ::: "memory");
      __builtin_amdgcn_sched_barrier(0);
    }

    // compute acc(t+1): h @ Wc^T, weights in f16 registers
    #pragma unroll
    for (int rr = 0; rr < 4; ++rr){ acc0[rr] = 0.f; acc1[rr] = 0.f; }
    #pragma unroll
    for (int c8 = 0; c8 < 4; ++c8){              // 8 k per chunk
      float4 p0 = *(const float4*)(hb0 + (c8 << 3));
      float4 p1 = *(const float4*)(hb0 + (c8 << 3) + 4);
      float4 q0 = *(const float4*)(hb1 + (c8 << 3));
      float4 q1 = *(const float4*)(hb1 + (c8 << 3) + 4);
      #pragma unroll
      for (int rr = 0; rr < 4; ++rr){
        ROWFMA8(wh[(rr << 4) + (c8 << 2)],     wh[(rr << 4) + (c8 << 2) + 1],
                wh[(rr << 4) + (c8 << 2) + 2], wh[(rr << 4) + (c8 << 2) + 3],
                acc0[rr], acc1[rr]);
      }
    }
  }
}

// In-place projection: out[row][n] = sum_k h[row][k]*Wout[n][k] + bout[n].
// Block owns 16 rows, staged to LDS first. 2 n-columns per pass halves the
// LDS read instruction count (proj is LDS-issue-bound at 1 wave/SIMD).
__global__ void __launch_bounds__(256, 1) proj_kernel(
    float* __restrict__ io, const float* __restrict__ Wout,
    const float* __restrict__ bout)
{
  extern __shared__ char smem[];
  float* alds = (float*)smem;                  // 16 x 2048 fp32 = 131072 B
  const int tid = threadIdx.x;
  const size_t rbase = (size_t)blockIdx.x * 16 * E;

  for (int idx = tid; idx < 8192; idx += 256){
    float4 v = *(const float4*)(io + rbase + ((size_t)idx << 2));
    *(float4*)(alds + (idx << 2)) = v;
  }
  __syncthreads();

  for (int p = 0; p < 4; ++p){
    const int n0 = (p << 8) + tid;             // column pair: n0, n0+1024
    const int n1 = n0 + 1024;
    const float* wr0 = Wout + (size_t)n0 * E;
    const float* wr1 = Wout + (size_t)n1 * E;
    float acc0[16], acc1[16];
    #pragma unroll
    for (int m = 0; m < 16; ++m){ acc0[m] = 0.0f; acc1[m] = 0.0f; }
    for (int kc = 0; kc < 256; ++kc){
      const float4 a0v = *(const float4*)(wr0 + (kc << 3));
      const float4 a1v = *(const float4*)(wr0 + (kc << 3) + 4);
      const float4 b0v = *(const float4*)(wr1 + (kc << 3));
      const float4 b1v = *(const float4*)(wr1 + (kc << 3) + 4);
      const float* ap = alds + (kc << 3);
      #pragma unroll
      for (int m = 0; m < 16; ++m){
        const float* a = ap + (m << 11);
        float4 x0 = *(const float4*)(a);
        float4 x1 = *(const float4*)(a + 4);
        acc0[m] = fmaf(a0v.x, x0.x, acc0[m]); acc0[m] = fmaf(a0v.y, x0.y, acc0[m]);
        acc0[m] = fmaf(a0v.z, x0.z, acc0[m]); acc0[m] = fmaf(a0v.w, x0.w, acc0[m]);
        acc0[m] = fmaf(a1v.x, x1.x, acc0[m]); acc0[m] = fmaf(a1v.y, x1.y, acc0[m]);
        acc0[m] = fmaf(a1v.z, x1.z, acc0[m]); acc0[m] = fmaf(a1v.w, x1.w, acc0[m]);
        acc1[m] = fmaf(b0v.x, x0.x, acc1[m]); acc1[m] = fmaf(b0v.y, x0.y, acc1[m]);
        acc1[m] = fmaf(b0v.z, x0.z, acc1[m]); acc1[m] = fmaf(b0v.w, x0.w, acc1[m]);
        acc1[m] = fmaf(b1v.x, x1.x, acc1[m]); acc1[m] = fmaf(b1v.y, x1.y, acc1[m]);
        acc1[m] = fmaf(b1v.z, x1.z, acc1[m]); acc1[m] = fmaf(b1v.w, x1.w, acc1[m]);
      }
    }
    const float bo0 = bout[n0];
    const float bo1 = bout[n1];
    #pragma unroll
    for (int m = 0; m < 16; ++m){
      io[rbase + ((size_t)m << 11) + n0] = acc0[m] + bo0;
      io[rbase + ((size_t)m << 11) + n1] = acc1[m] + bo1;
    }
  }
}

extern "C" void kernel_launch(void* const* d_in, const int* in_sizes, int n_in,
                              void* d_out, int out_size, void* d_ws, size_t ws_size,
                              hipStream_t stream)
{
  const float* xin  = (const float*)d_in[0];
  const float* Wih  = (const float*)d_in[1];
  const float* Whh  = (const float*)d_in[2];
  const float* bih  = (const float*)d_in[3];
  const float* bhh  = (const float*)d_in[4];
  const float* Wout = (const float*)d_in[5];
  const float* bout = (const float*)d_in[6];
  float* out = (float*)d_out;

  // chunk buffer: 2 parities x 4096 chunks x 8 B = 64 KB.
  // Poison 0xAAAAAAAA is never a valid tag (tags are 1..2047) -> no init pass.
  u64* chk = (u64*)d_ws;

  hipFuncSetAttribute((const void*)lstm_kernel,
                      hipFuncAttributeMaxDynamicSharedMemorySize, SMEM_MAIN);
  hipFuncSetAttribute((const void*)proj_kernel,
                      hipFuncAttributeMaxDynamicSharedMemorySize, SMEM_PROJ);

  void* args[] = { (void*)&xin, (void*)&Wih, (void*)&Whh, (void*)&bih, (void*)&bhh,
                   (void*)&chk, (void*)&out };
  hipLaunchCooperativeKernel((const void*)lstm_kernel, dim3(NBLK), dim3(NTHR),
                             args, SMEM_MAIN, stream);

  proj_kernel<<<256, 256, SMEM_PROJ, stream>>>(out, Wout, bout);
}